// Round 1
// baseline (291.707 us; speedup 1.0000x reference)
//
#include <hip/hip_runtime.h>

#define N_NODES 4096
#define C_CH    128
#define NSPEC   10
#define NCUB    165
#define NQUAD   45
#define NMONO   219   // 165 cubic + 45 quad + 9 linear

// ---- workspace layout (bytes); total = 13,049,824 (~12.5 MB) ----
#define WS_CNT    0            // 10 ints (species counts)
#define WS_LIST   256          // 10*4096 ints = 163840
#define WS_U3SYM  164096       // 4og*165*4k floats = 10560
#define WS_U2SYM  174656       // 4og*45*2k  floats = 1440
#define WS_COEFF  176096       // 1280*(219*4) floats = 4485120
#define WS_F      4661216      // 4096*128*4 floats  = 8388608

// ---------------------------------------------------------------------------
// Kernel 1: zero species counters + build permutation-symmetrized U3/U2.
// C3 over ordered triples == (sum over 6 orderings) * {1, 1/2, 1/6}.
// ---------------------------------------------------------------------------
__global__ void k_prep(const float* __restrict__ U3_0e, const float* __restrict__ U3_1o,
                       const float* __restrict__ U2_0e, const float* __restrict__ U2_1o,
                       int* __restrict__ cnt, float* __restrict__ U3sym,
                       float* __restrict__ U2sym) {
    int t = threadIdx.x;
    if (t < NSPEC) cnt[t] = 0;
    for (int task = t; task < 2640 + 360; task += blockDim.x) {
        if (task < 2640) {               // cubic: og(4) * m(165) * k(4)
            int og = task / 660;
            int r  = task - og * 660;
            int m  = r >> 2, k = r & 3;
            int a = 0, b = 0, d = 0;
            {   int idx = 0;
                for (int a0 = 0; a0 < 9; a0++)
                    for (int b0 = a0; b0 < 9; b0++)
                        for (int d0 = b0; d0 < 9; d0++) {
                            if (idx == m) { a = a0; b = b0; d = d0; }
                            idx++;
                        }
            }
            const float* U3 = (og == 0) ? U3_0e : U3_1o;
            int o = (og == 0) ? 0 : og - 1;
            const float* Ub = U3 + (size_t)o * 2916;   // [p][q][i][k] strides 324/36/4/1
            #define U3AT(p,q,i) Ub[((p)*9+(q))*36 + (i)*4 + k]
            float sum = U3AT(a,b,d) + U3AT(a,d,b) + U3AT(b,a,d)
                      + U3AT(b,d,a) + U3AT(d,a,b) + U3AT(d,b,a);
            #undef U3AT
            float sc = (a == b && b == d) ? (1.f/6.f)
                     : ((a == b || b == d || a == d) ? 0.5f : 1.f);
            U3sym[(og * 165 + m) * 4 + k] = sum * sc;
        } else {                          // quad: og(4) * q(45) * k(2)
            int t2 = task - 2640;
            int og = t2 / 90;
            int r  = t2 - og * 90;
            int q  = r >> 1, k = r & 1;
            int a = 0, b = 0;
            {   int idx = 0;
                for (int a0 = 0; a0 < 9; a0++)
                    for (int b0 = a0; b0 < 9; b0++) { if (idx == q) { a = a0; b = b0; } idx++; }
            }
            const float* U2 = (og == 0) ? U2_0e : U2_1o;
            int o = (og == 0) ? 0 : og - 1;
            const float* Ub = U2 + (size_t)o * 162;    // [p][i][k] strides 18/2/1
            float sum = Ub[(a*9 + b)*2 + k] + Ub[(b*9 + a)*2 + k];
            if (a == b) sum *= 0.5f;
            U2sym[(og * 45 + q) * 2 + k] = sum;
        }
    }
}

// ---------------------------------------------------------------------------
// Kernel 2: bucket node indices by species.
// ---------------------------------------------------------------------------
__global__ void k_lists(const int* __restrict__ specie, int* __restrict__ cnt,
                        int* __restrict__ list) {
    int i = blockIdx.x * blockDim.x + threadIdx.x;
    if (i < N_NODES) {
        int s = specie[i];
        int pos = atomicAdd(&cnt[s], 1);
        list[s * N_NODES + pos] = i;
    }
}

// ---------------------------------------------------------------------------
// Kernel 3: per-(s,c) monomial coefficients: contract Usym with W3/W2/W1.
// coeff layout: [s*128+c][mono 0..218][og 0..3]  (float4 per monomial)
// ---------------------------------------------------------------------------
__global__ void k_coeff(const float* __restrict__ U3sym, const float* __restrict__ U2sym,
                        const float* __restrict__ U1_0e, const float* __restrict__ U1_1o,
                        const float* __restrict__ W3_0e, const float* __restrict__ W3_1o,
                        const float* __restrict__ W2_0e, const float* __restrict__ W2_1o,
                        const float* __restrict__ W1_0e, const float* __restrict__ W1_1o,
                        float* __restrict__ coeff) {
    int blk = blockIdx.x;            // s*128 + c
    int s = blk >> 7, c = blk & 127;
    int t = threadIdx.x;
    if (t >= NMONO * 4) return;
    int m = t >> 2, og = t & 3;
    float val;
    if (m < NCUB) {
        const float* W3 = (og == 0) ? W3_0e : W3_1o;   // [s][k][c] strides 512/128/1
        const float* u  = U3sym + (og * 165 + m) * 4;
        val = u[0] * W3[s*512 +       c] + u[1] * W3[s*512 + 128 + c]
            + u[2] * W3[s*512 + 256 + c] + u[3] * W3[s*512 + 384 + c];
    } else if (m < NCUB + NQUAD) {
        int q = m - NCUB;
        const float* W2 = (og == 0) ? W2_0e : W2_1o;   // [s][k][c] strides 256/128/1
        const float* u  = U2sym + (og * 45 + q) * 2;
        val = u[0] * W2[s*256 + c] + u[1] * W2[s*256 + 128 + c];
    } else {
        int l = m - (NCUB + NQUAD);
        const float* U1 = (og == 0) ? U1_0e : U1_1o;   // [o][i][k=1]
        const float* W1 = (og == 0) ? W1_0e : W1_1o;   // [s][1][c]
        int o = (og == 0) ? 0 : og - 1;
        val = U1[o * 9 + l] * W1[s * 128 + c];
    }
    coeff[(size_t)blk * (NMONO * 4) + t] = val;
}

// ---------------------------------------------------------------------------
// Kernel 4: main contraction. Block = (s,c); coefficients are wave-uniform
// (blockIdx-derived) -> compiler scalarizes to s_load; coefficient rides the
// SGPR operand of v_fmac. 2 nodes per thread amortize coefficient fetch.
// f output: [n][c][og0..3] as float4.
// ---------------------------------------------------------------------------
__global__ __launch_bounds__(256) void k_main(const float* __restrict__ x,
        const int* __restrict__ cnt, const int* __restrict__ list,
        const float* __restrict__ coeff, float* __restrict__ fout) {
    int blk = blockIdx.x;
    int s = blk >> 7, c = blk & 127;
    int n = cnt[s];
    if (n == 0) return;
    const float* __restrict__ cf  = coeff + (size_t)blk * (NMONO * 4);
    const int*   __restrict__ lst = list + s * N_NODES;

    for (int base = 0; base < n; base += 512) {
        int i0 = base + (int)threadIdx.x;
        int i1 = i0 + 256;
        int b0 = lst[i0 < n ? i0 : 0];
        int b1 = lst[i1 < n ? i1 : 0];
        const float* xp0 = x + ((size_t)b0 * C_CH + c) * 9;
        const float* xp1 = x + ((size_t)b1 * C_CH + c) * 9;
        float x0[9], x1[9];
        #pragma unroll
        for (int i = 0; i < 9; i++) { x0[i] = xp0[i]; x1[i] = xp1[i]; }

        float a0[4] = {0.f, 0.f, 0.f, 0.f};
        float a1[4] = {0.f, 0.f, 0.f, 0.f};
        int m3 = 0, m2 = 0;
        #pragma unroll
        for (int a = 0; a < 9; a++) {
            {   // linear term
                const float* cl = cf + (210 + a) * 4;
                #pragma unroll
                for (int e = 0; e < 4; e++) { a0[e] = fmaf(cl[e], x0[a], a0[e]);
                                              a1[e] = fmaf(cl[e], x1[a], a1[e]); }
            }
            #pragma unroll
            for (int b = a; b < 9; b++) {
                float p0 = x0[a] * x0[b], p1 = x1[a] * x1[b];
                const float* cq = cf + (165 + m2) * 4; m2++;
                #pragma unroll
                for (int e = 0; e < 4; e++) { a0[e] = fmaf(cq[e], p0, a0[e]);
                                              a1[e] = fmaf(cq[e], p1, a1[e]); }
                #pragma unroll
                for (int d = b; d < 9; d++) {
                    const float* c3 = cf + m3 * 4; m3++;
                    float q0 = p0 * x0[d], q1 = p1 * x1[d];
                    #pragma unroll
                    for (int e = 0; e < 4; e++) { a0[e] = fmaf(c3[e], q0, a0[e]);
                                                  a1[e] = fmaf(c3[e], q1, a1[e]); }
                }
            }
        }
        if (i0 < n) *(float4*)&fout[((size_t)b0 * C_CH + c) * 4] = make_float4(a0[0], a0[1], a0[2], a0[3]);
        if (i1 < n) *(float4*)&fout[((size_t)b1 * C_CH + c) * 4] = make_float4(a1[0], a1[1], a1[2], a1[3]);
    }
}

// ---------------------------------------------------------------------------
// Kernel 5: epilogue linear. Block = (n-tile of 64, jg of 8); lane = node,
// wave owns 16 contiguous output channels (uniform -> W via s_load_dwordx16).
// y = scale * f @ Wlin (+ bias on 0e). Transpose through LDS for coalesced
// stores. out col: o==0 -> m ; o>=1 -> 128 + m*3 + (o-1).
// ---------------------------------------------------------------------------
__global__ __launch_bounds__(256) void k_epi(const float* __restrict__ f,
        const float* __restrict__ W0, const float* __restrict__ W1,
        const float* __restrict__ bias, float* __restrict__ out) {
    __shared__ float smem[128 * 65];        // ftile [c][n(64)+pad]; reused as trbuf [j][n]
    int bx = blockIdx.x;
    int ntile = bx >> 3, jg = bx & 7;       // 64 n-tiles x 8 j-groups of 64
    int n0 = ntile * 64;
    int t  = threadIdx.x;
    int o  = jg >> 1;                        // output component 0..3 (uniform per block)

    // stage f[., ., o] tile: 64 n x 128 c -> smem[c][n]
    #pragma unroll
    for (int r = 0; r < 32; ++r) {
        int flat = r * 256 + t;              // 8192 = 64n * 128c
        int n = flat >> 7, c = flat & 127;
        smem[c * 65 + n] = f[(size_t)(n0 + n) * 512 + c * 4 + o];
    }
    __syncthreads();

    int w    = __builtin_amdgcn_readfirstlane((int)(t >> 6));
    int lane = t & 63;
    int mb   = (jg & 1) * 64 + w * 16;       // wave's m base (uniform)
    const float* __restrict__ Wsel = (o == 0) ? W0 : W1;

    float acc[16];
    #pragma unroll
    for (int jj = 0; jj < 16; jj++) acc[jj] = 0.f;

    #pragma unroll 4
    for (int c = 0; c < 128; ++c) {
        float fv = smem[c * 65 + lane];
        #pragma unroll
        for (int jj = 0; jj < 16; jj++)
            acc[jj] = fmaf(fv, Wsel[c * 128 + mb + jj], acc[jj]);
    }
    __syncthreads();                          // all waves done reading ftile

    const float scale = 0.08838834764831845f; // 1/sqrt(128)
    #pragma unroll
    for (int jj = 0; jj < 16; jj++) {
        float v = acc[jj] * scale;
        if (o == 0) v += bias[mb + jj];
        smem[(w * 16 + jj) * 65 + lane] = v;  // trbuf[j_local][n]
    }
    __syncthreads();

    #pragma unroll
    for (int r = 0; r < 16; ++r) {
        int flat = r * 256 + t;               // 4096 = 64j * 64n
        int jl = flat & 63, n = flat >> 6;
        int m  = (jg & 1) * 64 + jl;
        int col = (o == 0) ? m : (128 + m * 3 + (o - 1));
        out[(size_t)(n0 + n) * 512 + col] = smem[jl * 65 + n];
    }
}

extern "C" void kernel_launch(void* const* d_in, const int* in_sizes, int n_in,
                              void* d_out, int out_size, void* d_ws, size_t ws_size,
                              hipStream_t stream) {
    const float* x     = (const float*)d_in[0];
    const int*   spec  = (const int*)  d_in[1];
    const float* U3_0e = (const float*)d_in[2];
    const float* U2_0e = (const float*)d_in[3];
    const float* U1_0e = (const float*)d_in[4];
    const float* W3_0e = (const float*)d_in[5];
    const float* W2_0e = (const float*)d_in[6];
    const float* W1_0e = (const float*)d_in[7];
    const float* U3_1o = (const float*)d_in[8];
    const float* U2_1o = (const float*)d_in[9];
    const float* U1_1o = (const float*)d_in[10];
    const float* W3_1o = (const float*)d_in[11];
    const float* W2_1o = (const float*)d_in[12];
    const float* W1_1o = (const float*)d_in[13];
    const float* Wlin0 = (const float*)d_in[14];
    const float* Wlin1 = (const float*)d_in[15];
    const float* bias0 = (const float*)d_in[16];
    float* out = (float*)d_out;

    char* ws = (char*)d_ws;
    int*   cnt   = (int*)  (ws + WS_CNT);
    int*   list  = (int*)  (ws + WS_LIST);
    float* U3sym = (float*)(ws + WS_U3SYM);
    float* U2sym = (float*)(ws + WS_U2SYM);
    float* coeff = (float*)(ws + WS_COEFF);
    float* f     = (float*)(ws + WS_F);
    (void)in_sizes; (void)n_in; (void)out_size; (void)ws_size;

    hipLaunchKernelGGL(k_prep,  dim3(1),    dim3(1024), 0, stream,
                       U3_0e, U3_1o, U2_0e, U2_1o, cnt, U3sym, U2sym);
    hipLaunchKernelGGL(k_lists, dim3(16),   dim3(256),  0, stream, spec, cnt, list);
    hipLaunchKernelGGL(k_coeff, dim3(1280), dim3(896),  0, stream,
                       U3sym, U2sym, U1_0e, U1_1o, W3_0e, W3_1o,
                       W2_0e, W2_1o, W1_0e, W1_1o, coeff);
    hipLaunchKernelGGL(k_main,  dim3(1280), dim3(256),  0, stream, x, cnt, list, coeff, f);
    hipLaunchKernelGGL(k_epi,   dim3(512),  dim3(256),  0, stream, f, Wlin0, Wlin1, bias0, out);
}